// Round 3
// baseline (295.432 us; speedup 1.0000x reference)
//
#include <hip/hip_runtime.h>

// out[b,v,c] = sum_k evecs[b,v,k]^2 * exp(-evals[b,k] * scale[c])
// scale[c] = 10^(-2 + 2c/15). B=8, V=50000, K=128, CNT=16, fp32.
//
// R3 structure:
//  - kernel1 precomputes coefT[b][c][k] (16 KB total) into d_ws.
//  - main kernel: TPB=64 (1 wave/block), 256 rows/block (TILE=4/thread).
//    evecs staged through LDS in 32-k chunks, fully coalesced (8 lanes read
//    one row's contiguous 128 B). Manual double-pipeline: chunk kc+1's
//    global loads are in flight (in VGPRs) while chunk kc computes.
//  - coef read from LDS as wave-uniform b128 broadcasts, amortized over
//    TILE=4 rows (R0 measured: broadcast b128 ~12cyc return-BW, was the
//    62us bound at TILE=1).

constexpr int B_   = 8;
constexpr int V_   = 50000;
constexpr int K_   = 128;
constexpr int CNT  = 16;
constexpr int TPB  = 64;
constexpr int ROWS = 256;           // rows per block
constexpr int TILE = ROWS / TPB;    // 4
constexpr int CK   = 32;            // k-chunk (floats) = 128 B per row
constexpr int NCH  = K_ / CK;       // 4
constexpr int STR  = CK + 4;        // 36-float LDS row stride (bank spread)
constexpr int F4PT = ROWS * (CK/4) / TPB;  // stage float4 per thread = 32

__global__ void fill_coef(const float* __restrict__ evals,
                          float* __restrict__ coefT) {
    const int b = blockIdx.x;
    for (int i = threadIdx.x; i < CNT * K_; i += blockDim.x) {
        const int c = i >> 7;
        const int k = i & (K_ - 1);
        const float s = powf(10.0f, -2.0f + (float)c * (2.0f / 15.0f));
        coefT[(long)b * CNT * K_ + i] = expf(-evals[b * K_ + k] * s);
    }
}

__global__ __launch_bounds__(TPB, 1) void heat_main(
    const float* __restrict__ evecs,   // [B, V, K]
    const float* __restrict__ coefT,   // [B, CNT, K]
    float* __restrict__ out)           // [B, V, CNT]
{
    __shared__ float4 coef4[CNT * K_ / 4];   // 8 KB, [c][j]
    __shared__ float  ebuf[ROWS * STR];      // 36 KB

    const int b   = blockIdx.y;
    const int tid = threadIdx.x;
    const int row0 = blockIdx.x * ROWS;

    // coef table -> LDS: 512 float4, 8 per thread, coalesced.
    {
        const float4* src = (const float4*)(coefT + (long)b * CNT * K_);
#pragma unroll
        for (int i = 0; i < 8; ++i)
            coef4[i * TPB + tid] = src[i * TPB + tid];
    }

    const float* ebase = evecs + (long)b * V_ * K_;

    float4 stage[F4PT];

    // f = i*64+tid; local row = f>>3 (8 lanes per row, 128 B contiguous).
    auto issue = [&](int kc) {
#pragma unroll
        for (int i = 0; i < F4PT; ++i) {
            const int f = i * TPB + tid;
            int row = row0 + (f >> 3);
            row = row < V_ ? row : V_ - 1;     // clamp, stores are predicated
            const int q = f & 7;
            stage[i] = *(const float4*)(ebase + (long)row * K_ + kc * CK + q * 4);
        }
    };
    auto commit = [&]() {
#pragma unroll
        for (int i = 0; i < F4PT; ++i) {
            const int f = i * TPB + tid;
            const int lrow = f >> 3;
            const int q = f & 7;
            *(float4*)(&ebuf[lrow * STR + q * 4]) = stage[i];
        }
    };

    float acc[TILE][CNT];
#pragma unroll
    for (int r = 0; r < TILE; ++r)
#pragma unroll
        for (int c = 0; c < CNT; ++c) acc[r][c] = 0.0f;

    issue(0);

    for (int kc = 0; kc < NCH; ++kc) {
        __syncthreads();               // prev chunk's LDS reads done
        commit();                      // vmcnt wait inserted by compiler
        if (kc + 1 < NCH) issue(kc + 1);  // next chunk in flight during compute
        __syncthreads();               // writes visible

#pragma unroll
        for (int q = 0; q < CK / 4; ++q) {      // 8 float4 per row-chunk
            float4 sq[TILE];
#pragma unroll
            for (int r = 0; r < TILE; ++r) {
                const int lrow = tid + r * TPB;
                const float4 e = *(const float4*)(&ebuf[lrow * STR + q * 4]);
                sq[r].x = e.x * e.x;
                sq[r].y = e.y * e.y;
                sq[r].z = e.z * e.z;
                sq[r].w = e.w * e.w;
            }
#pragma unroll
            for (int c = 0; c < CNT; ++c) {
                // wave-uniform LDS broadcast; one read feeds TILE*4=16 FMAs
                const float4 w = coef4[c * (K_ / 4) + kc * (CK / 4) + q];
#pragma unroll
                for (int r = 0; r < TILE; ++r) {
                    acc[r][c] += sq[r].x * w.x;
                    acc[r][c] += sq[r].y * w.y;
                    acc[r][c] += sq[r].z * w.z;
                    acc[r][c] += sq[r].w * w.w;
                }
            }
        }
    }

#pragma unroll
    for (int r = 0; r < TILE; ++r) {
        const int row = row0 + tid + r * TPB;
        if (row < V_) {
            float4* o = (float4*)(out + ((long)b * V_ + row) * CNT);
#pragma unroll
            for (int qq = 0; qq < 4; ++qq)
                o[qq] = make_float4(acc[r][4 * qq + 0], acc[r][4 * qq + 1],
                                    acc[r][4 * qq + 2], acc[r][4 * qq + 3]);
        }
    }
}

extern "C" void kernel_launch(void* const* d_in, const int* in_sizes, int n_in,
                              void* d_out, int out_size, void* d_ws, size_t ws_size,
                              hipStream_t stream) {
    const float* evals = (const float*)d_in[0];  // [8,128]
    const float* evecs = (const float*)d_in[1];  // [8,50000,128]
    float* out   = (float*)d_out;                // [8,50000,16]
    float* coefT = (float*)d_ws;                 // [8,16,128] = 16 KB

    fill_coef<<<B_, 256, 0, stream>>>(evals, coefT);

    dim3 grid((V_ + ROWS - 1) / ROWS, B_);
    heat_main<<<grid, TPB, 0, stream>>>(evecs, coefT, out);
}

// Round 4
// 114.657 us; speedup vs baseline: 2.5767x; 2.5767x over previous
//
#include <hip/hip_runtime.h>

// out[b,v,c] = sum_k evecs[b,v,k]^2 * exp(-evals[b,k] * scale[c])
// scale[c] = 10^(-2 + 2c/15). B=8, V=50000, K=128, CNT=16, fp32.
//
// R4 structure (fixes R3's occupancy/spill, keeps its coalesced staging):
//  - TPB=256 (4 waves), ROWS=256 rows/block, k chunked CK=32 (4 chunks).
//  - Stage evecs chunk into LDS coalescedly (8 lanes = one row's 128 B),
//    via regs (8 float4/thread) with T14 issue-early/commit-late pipeline.
//  - c-SPLIT ACROSS WAVES: wave w computes c = 4w..4w+3 for ALL 256 rows
//    (lane owns rows lane, lane+64, +128, +192 read from LDS). Coef
//    broadcasts amortized 16x; e-rows shared by all 4 waves from LDS.
//  - ebuf padded stride 9 float4 (36 words == 4 mod 32) -> rows spread
//    over all 8 bank groups; both ds_write and ds_read at baseline cost.
//  - VGPR budget ~100 (stage 32 + acc 16): no scratch spill (R3: 222 MB
//    WRITE_SIZE was spill traffic).

constexpr int B_   = 8;
constexpr int V_   = 50000;
constexpr int K_   = 128;
constexpr int CNT  = 16;
constexpr int TPB  = 256;
constexpr int ROWS = 256;
constexpr int CK   = 32;            // k-chunk (floats)
constexpr int NCH  = K_ / CK;       // 4
constexpr int F4C  = CK / 4;        // 8 float4 per row-chunk
constexpr int ESTR = F4C + 1;       // 9 float4 stride (bank spread)
constexpr int SPT  = ROWS * F4C / TPB;  // stage float4 per thread = 8

__global__ void fill_coef(const float* __restrict__ evals,
                          float* __restrict__ coefT) {
    const int b = blockIdx.x;
    for (int i = threadIdx.x; i < CNT * K_; i += blockDim.x) {
        const int c = i >> 7;
        const int k = i & (K_ - 1);
        const float s = powf(10.0f, -2.0f + (float)c * (2.0f / 15.0f));
        coefT[(long)b * CNT * K_ + i] = expf(-evals[b * K_ + k] * s);
    }
}

__global__ __launch_bounds__(TPB) void heat_main(
    const float* __restrict__ evecs,   // [B, V, K]
    const float* __restrict__ coefT,   // [B, CNT, K]
    float* __restrict__ out)           // [B, V, CNT]
{
    __shared__ float4 coef4[CNT * (K_ / 4)];   // [c][j] 8 KB
    __shared__ float4 ebuf[ROWS * ESTR];       // 36.9 KB

    const int b    = blockIdx.y;
    const int tid  = threadIdx.x;
    const int w    = tid >> 6;        // wave id -> c-group
    const int lane = tid & 63;
    const int row0 = blockIdx.x * ROWS;

    // coef -> LDS: 512 float4, 2 per thread, coalesced.
    {
        const float4* src = (const float4*)(coefT + (long)b * CNT * K_);
        coef4[tid]       = src[tid];
        coef4[tid + TPB] = src[tid + TPB];
    }

    const float* ebase = evecs + (long)b * V_ * K_;

    float4 stage[SPT];

    // f = i*TPB + tid; row = f>>3 (8 lanes per row, 128 B contiguous), s = f&7.
    auto issue = [&](int ch) {
#pragma unroll
        for (int i = 0; i < SPT; ++i) {
            const int f = i * TPB + tid;
            int row = row0 + (f >> 3);
            row = row < V_ ? row : V_ - 1;   // clamp; stores are predicated
            const int s = f & 7;
            stage[i] = *(const float4*)(ebase + (long)row * K_ + ch * CK + s * 4);
        }
    };
    auto commit = [&]() {
#pragma unroll
        for (int i = 0; i < SPT; ++i) {
            const int f = i * TPB + tid;
            ebuf[(f >> 3) * ESTR + (f & 7)] = stage[i];
        }
    };

    float4 acc[4];  // acc[rr] = {c0,c1,c2,c3} for row rr*64+lane
#pragma unroll
    for (int rr = 0; rr < 4; ++rr) acc[rr] = make_float4(0.f, 0.f, 0.f, 0.f);

    issue(0);

    for (int ch = 0; ch < NCH; ++ch) {
        __syncthreads();                 // prev chunk's LDS reads complete
        commit();                        // compiler inserts vmcnt wait
        if (ch + 1 < NCH) issue(ch + 1); // next chunk's loads fly during compute
        __syncthreads();                 // staged data visible

#pragma unroll
        for (int j = 0; j < F4C; ++j) {
            // 4 wave-uniform coef broadcasts for this wave's c-group
            float4 w0 = coef4[(4 * w + 0) * (K_ / 4) + ch * F4C + j];
            float4 w1 = coef4[(4 * w + 1) * (K_ / 4) + ch * F4C + j];
            float4 w2 = coef4[(4 * w + 2) * (K_ / 4) + ch * F4C + j];
            float4 w3 = coef4[(4 * w + 3) * (K_ / 4) + ch * F4C + j];
#pragma unroll
            for (int rr = 0; rr < 4; ++rr) {
                const float4 e = ebuf[(rr * 64 + lane) * ESTR + j];
                const float sx = e.x * e.x, sy = e.y * e.y;
                const float sz = e.z * e.z, sw = e.w * e.w;
                acc[rr].x += sx * w0.x; acc[rr].x += sy * w0.y;
                acc[rr].x += sz * w0.z; acc[rr].x += sw * w0.w;
                acc[rr].y += sx * w1.x; acc[rr].y += sy * w1.y;
                acc[rr].y += sz * w1.z; acc[rr].y += sw * w1.w;
                acc[rr].z += sx * w2.x; acc[rr].z += sy * w2.y;
                acc[rr].z += sz * w2.z; acc[rr].z += sw * w2.w;
                acc[rr].w += sx * w3.x; acc[rr].w += sy * w3.y;
                acc[rr].w += sz * w3.z; acc[rr].w += sw * w3.w;
            }
        }
    }

    // Store: thread owns rows rr*64+lane, c's 4w..4w+3 -> one float4 each.
#pragma unroll
    for (int rr = 0; rr < 4; ++rr) {
        const int row = row0 + rr * 64 + lane;
        if (row < V_)
            *(float4*)(out + ((long)b * V_ + row) * CNT + 4 * w) = acc[rr];
    }
}

extern "C" void kernel_launch(void* const* d_in, const int* in_sizes, int n_in,
                              void* d_out, int out_size, void* d_ws, size_t ws_size,
                              hipStream_t stream) {
    const float* evals = (const float*)d_in[0];  // [8,128]
    const float* evecs = (const float*)d_in[1];  // [8,50000,128]
    float* out   = (float*)d_out;                // [8,50000,16]
    float* coefT = (float*)d_ws;                 // [8,16,128] = 16 KB

    fill_coef<<<B_, 256, 0, stream>>>(evals, coefT);

    dim3 grid((V_ + ROWS - 1) / ROWS, B_);
    heat_main<<<grid, TPB, 0, stream>>>(evecs, coefT, out);
}

// Round 5
// 89.130 us; speedup vs baseline: 3.3146x; 1.2864x over previous
//
#include <hip/hip_runtime.h>

// out[b,v,c] = sum_k evecs[b,v,k]^2 * exp(-evals[b,k] * scale[c])
// scale[c] = 10^(-2 + 2c/15). B=8, V=50000, K=128, CNT=16, fp32.
//
// R5: pure streaming, NO LDS in the hot kernel.
//  - 1 thread = 1 row (like R0): evecs bytes each read exactly once,
//    thread-private lines, 64-B contiguous output stores (fixes R4's 4x
//    write amplification from scattered 16-B stores).
//  - coef table (precomputed in d_ws by fill_coef) is read at wave-uniform
//    addresses -> compiler emits s_load_dwordx4 + v_fmac v,s,v (scalar
//    path, 1 SGPR operand per VALU op is legal). Zero LDS-pipe traffic --
//    removes R0's measured 62us ds_read_b128 broadcast bound.
//  - j-loads batched 8-at-a-time per 32-k block: both of the thread's
//    128-B lines fetched back-to-back, consumed from VGPRs.
//  - No barriers in hot loop, no LDS -> occupancy limited only by VGPR.

constexpr int B_   = 8;
constexpr int V_   = 50000;
constexpr int K_   = 128;
constexpr int CNT  = 16;
constexpr int TPB  = 256;

__global__ void fill_coef(const float* __restrict__ evals,
                          float* __restrict__ coefT) {
    const int b = blockIdx.x;
    for (int i = threadIdx.x; i < CNT * K_; i += blockDim.x) {
        const int c = i >> 7;
        const int k = i & (K_ - 1);
        const float s = powf(10.0f, -2.0f + (float)c * (2.0f / 15.0f));
        coefT[(long)b * CNT * K_ + i] = expf(-evals[b * K_ + k] * s);
    }
}

__global__ __launch_bounds__(TPB) void heat_main(
    const float* __restrict__ evecs,   // [B, V, K]
    const float* __restrict__ coefT,   // [B, CNT, K]
    float* __restrict__ out)           // [B, V, CNT]
{
    const int b = blockIdx.y;
    const int v = blockIdx.x * TPB + threadIdx.x;
    if (v >= V_) return;

    // Wave-uniform base -> scalar loads.
    const float* __restrict__ cf = coefT + (long)b * CNT * K_;

    const float4* __restrict__ row =
        (const float4*)(evecs + ((long)b * V_ + v) * K_);

    float acc[CNT];
#pragma unroll
    for (int c = 0; c < CNT; ++c) acc[c] = 0.0f;

#pragma unroll
    for (int kb = 0; kb < K_ / 32; ++kb) {       // 4 blocks of 32 k
        // Batch-issue this thread's two full 128-B lines.
        float4 e[8];
#pragma unroll
        for (int j = 0; j < 8; ++j) e[j] = row[kb * 8 + j];

#pragma unroll
        for (int j = 0; j < 8; ++j) {
            const float sx = e[j].x * e[j].x;
            const float sy = e[j].y * e[j].y;
            const float sz = e[j].z * e[j].z;
            const float sw = e[j].w * e[j].w;
            const int k0 = kb * 32 + j * 4;
#pragma unroll
            for (int c = 0; c < CNT; ++c) {
                // Uniform address: s_load_dwordx4; FMA reads SGPR directly.
                const float* w = cf + c * K_ + k0;
                acc[c] += sx * w[0];
                acc[c] += sy * w[1];
                acc[c] += sz * w[2];
                acc[c] += sw * w[3];
            }
        }
    }

    float4* o = (float4*)(out + ((long)b * V_ + v) * CNT);
#pragma unroll
    for (int q = 0; q < 4; ++q)
        o[q] = make_float4(acc[4 * q + 0], acc[4 * q + 1],
                           acc[4 * q + 2], acc[4 * q + 3]);
}

extern "C" void kernel_launch(void* const* d_in, const int* in_sizes, int n_in,
                              void* d_out, int out_size, void* d_ws, size_t ws_size,
                              hipStream_t stream) {
    const float* evals = (const float*)d_in[0];  // [8,128]
    const float* evecs = (const float*)d_in[1];  // [8,50000,128]
    float* out   = (float*)d_out;                // [8,50000,16]
    float* coefT = (float*)d_ws;                 // [8,16,128] = 16 KB

    fill_coef<<<B_, 256, 0, stream>>>(evals, coefT);

    dim3 grid((V_ + TPB - 1) / TPB, B_);
    heat_main<<<grid, TPB, 0, stream>>>(evecs, coefT, out);
}

// Round 6
// 47.194 us; speedup vs baseline: 6.2599x; 1.8886x over previous
//
#include <hip/hip_runtime.h>

// out[b,v,c] = sum_k evecs[b,v,k]^2 * exp(-evals[b,k] * scale[c])
// scale[c] = 10^(-2 + 2c/15). B=8, V=50000, K=128, CNT=16. fp32 in/out.
//
// R6: MFMA formulation. out_b = (evecs_b^2) . coef_b^T is a
// (50000x128)x(128x16) bf16 GEMM per b (fp32 accumulate).
//  - B-operand (coef, 16x128) loaded once per tile as 4 bf16x8 fragments
//    held in VGPRs -> NO LDS, NO SMEM in the hot loop (R0's 65us was
//    LDS-return-BW bound at 12 cyc/b128; R5's 89us was scalar-load
//    latency bound; this removes both pipes entirely).
//  - A-fragments load straight from global in fragment order: lane l
//    reads row (l&15), floats k = m*32 + (l>>4)*8. The wave's 8 dwordx4
//    per tile fully consume 16 rows x 512 B in one burst -> perfect
//    cache-line utilization (fixes R1's 1.9x over-fetch mechanism).
//  - D layout (m89-verified): col=lane&15, row=(lane>>4)*4+reg ->
//    16 lanes store 64 B contiguous per output row (fixes R4's 4x
//    write amplification).
//  - squaring + f32->bf16 (RNE bit-trick) in registers, fp32 MFMA accum.
//    Error budget ~0.3 << 4.32 threshold (threshold is bf16-sized).

constexpr int B_  = 8;
constexpr int V_  = 50000;
constexpr int K_  = 128;
constexpr int CNT = 16;
constexpr int TPB = 256;                 // 4 waves/block
constexpr int VT  = V_ / 16;             // 3125 row-tiles per batch
constexpr int TOT = B_ * VT;             // 25000 tiles
constexpr int TPW = 2;                   // tiles per wave
constexpr int NBLK = TOT / (4 * TPW);    // 3125 blocks, exact (no tail)

typedef short bf16x8 __attribute__((ext_vector_type(8)));  // 4 VGPRs
typedef float f32x4  __attribute__((ext_vector_type(4)));

static __device__ __forceinline__ unsigned short f2bf(float f) {
    union { float f; unsigned u; } v; v.f = f;
    unsigned r = v.u + 0x7FFFu + ((v.u >> 16) & 1u);   // round-nearest-even
    return (unsigned short)(r >> 16);
}

__global__ void fill_coef(const float* __restrict__ evals,
                          unsigned short* __restrict__ coefB) {  // [B,CNT,K] bf16
    const int b = blockIdx.x;
    for (int i = threadIdx.x; i < CNT * K_; i += blockDim.x) {
        const int c = i >> 7;
        const int k = i & (K_ - 1);
        const float s = powf(10.0f, -2.0f + (float)c * (2.0f / 15.0f));
        coefB[b * CNT * K_ + i] = f2bf(expf(-evals[b * K_ + k] * s));
    }
}

__global__ __launch_bounds__(TPB) void heat_mfma(
    const float* __restrict__ evecs,           // [B, V, K] fp32
    const unsigned short* __restrict__ coefB,  // [B, CNT, K] bf16
    float* __restrict__ out)                   // [B, V, CNT] fp32
{
    const int lane = threadIdx.x & 63;
    const int gw   = blockIdx.x * 4 + (threadIdx.x >> 6);  // global wave id
    const int r    = lane & 15;   // A-row-in-tile / B-col(c) / D-col(c)
    const int kg   = lane >> 4;   // k-subgroup (8 elems each)

    const int t0 = gw * TPW;

    float4 a[TPW][8];      // raw fp32 A rows (2 lines/tile, burst-consumed)
    bf16x8 bf[TPW][4];     // B fragments (coef^T), stay in VGPRs
    long   vbase[TPW];

    // ---- issue ALL loads for both tiles (burst: lines die immediately) ----
#pragma unroll
    for (int t = 0; t < TPW; ++t) {
        const int tile = t0 + t;
        const int b    = tile / VT;          // constexpr magic-mul
        const int vt   = tile - b * VT;
        vbase[t] = (long)b * V_ + (long)vt * 16;

        const float* arow =
            evecs + (vbase[t] + r) * K_ + kg * 8;
        const unsigned short* brow =
            coefB + ((long)b * CNT + r) * K_ + kg * 8;
#pragma unroll
        for (int m = 0; m < 4; ++m) {
            a[t][2 * m]     = *(const float4*)(arow + m * 32);
            a[t][2 * m + 1] = *(const float4*)(arow + m * 32 + 4);
            bf[t][m]        = *(const bf16x8*)(brow + m * 32);
        }
    }

    // ---- compute + store ----
#pragma unroll
    for (int t = 0; t < TPW; ++t) {
        f32x4 acc = {0.f, 0.f, 0.f, 0.f};
#pragma unroll
        for (int m = 0; m < 4; ++m) {
            const float4 e0 = a[t][2 * m];
            const float4 e1 = a[t][2 * m + 1];
            bf16x8 af;
            af[0] = (short)f2bf(e0.x * e0.x);
            af[1] = (short)f2bf(e0.y * e0.y);
            af[2] = (short)f2bf(e0.z * e0.z);
            af[3] = (short)f2bf(e0.w * e0.w);
            af[4] = (short)f2bf(e1.x * e1.x);
            af[5] = (short)f2bf(e1.y * e1.y);
            af[6] = (short)f2bf(e1.z * e1.z);
            af[7] = (short)f2bf(e1.w * e1.w);
            acc = __builtin_amdgcn_mfma_f32_16x16x32_bf16(af, bf[t][m], acc,
                                                          0, 0, 0);
        }
        // D: col = lane&15 (=c), row = kg*4 + i. 16 lanes -> 64 B contiguous.
#pragma unroll
        for (int i = 0; i < 4; ++i)
            out[(vbase[t] + kg * 4 + i) * CNT + r] = acc[i];
    }
}

extern "C" void kernel_launch(void* const* d_in, const int* in_sizes, int n_in,
                              void* d_out, int out_size, void* d_ws, size_t ws_size,
                              hipStream_t stream) {
    const float* evals = (const float*)d_in[0];  // [8,128]
    const float* evecs = (const float*)d_in[1];  // [8,50000,128]
    float* out = (float*)d_out;                  // [8,50000,16]
    unsigned short* coefB = (unsigned short*)d_ws;  // [8,16,128] bf16 = 32 KB

    fill_coef<<<B_, 256, 0, stream>>>(evals, coefB);
    heat_mfma<<<NBLK, TPB, 0, stream>>>(evecs, coefB, out);
}

// Round 7
// 39.603 us; speedup vs baseline: 7.4598x; 1.1917x over previous
//
#include <hip/hip_runtime.h>

// out[b,v,c] = sum_k evecs[b,v,k]^2 * exp(-evals[b,k] * scale[c])
// scale[c] = 10^(-2 + 2c/15). B=8, V=50000, K=128, CNT=16. fp32 in/out.
//
// R7 = R6 (MFMA, zero-LDS, burst-coalesced) + fusion:
//  - coef B-fragments computed IN REGISTERS from evals (32 v_exp_f32/lane,
//    overlapped with the A-load HBM latency) -> removes the serialized
//    fill_coef pre-kernel (~5us of graph-critical-path) and d_ws entirely.
//  - nontemporal stores for out (never re-read; keeps 25.6 MB out of L2).
//  - A-fragments: lane l reads rows (l&15), k = (l>>4)*8 + m*32 -> each
//    dwordx4 instruction consumes 16 full 128-B lines exactly once.
//  - D layout (m89): col=lane&15 (=c), row=(lane>>4)*4+i -> 16 lanes store
//    64 B contiguous per output row; no write amplification.
//  - fp32 squares -> bf16 (RNE) -> mfma_f32_16x16x32_bf16, fp32 accum.

constexpr int B_  = 8;
constexpr int V_  = 50000;
constexpr int K_  = 128;
constexpr int CNT = 16;
constexpr int TPB = 256;                    // 4 waves/block
constexpr int VT  = V_ / 16;                // 3125 row-tiles per batch (exact)
constexpr int TPW = 2;                      // tiles per wave
constexpr int TPBLK = 4 * TPW;              // 8 tiles per block
constexpr int GX  = (VT + TPBLK - 1) / TPBLK;  // 391 blocks per batch

typedef short bf16x8 __attribute__((ext_vector_type(8)));  // 4 VGPRs
typedef float f32x4  __attribute__((ext_vector_type(4)));

static __device__ __forceinline__ unsigned short f2bf(float f) {
    union { float f; unsigned u; } v; v.f = f;
    unsigned r = v.u + 0x7FFFu + ((v.u >> 16) & 1u);   // round-nearest-even
    return (unsigned short)(r >> 16);
}

__global__ __launch_bounds__(TPB) void heat_mfma(
    const float* __restrict__ evals,   // [B, K]
    const float* __restrict__ evecs,   // [B, V, K]
    float* __restrict__ out)           // [B, V, CNT]
{
    const int lane = threadIdx.x & 63;
    const int wid  = threadIdx.x >> 6;
    const int b    = blockIdx.y;
    const int r    = lane & 15;   // A row-in-tile / B,D col (=c)
    const int kg   = lane >> 4;   // k-subgroup (8 floats each)

    const int vt0 = (blockIdx.x * 4 + wid) * TPW;

    // ---- issue ALL A loads first (burst; lines fully consumed per inst) ----
    float4 a[TPW][8];
    long   vbase[TPW];
    bool   valid[TPW];
#pragma unroll
    for (int t = 0; t < TPW; ++t) {
        int vt   = vt0 + t;
        valid[t] = (vt < VT);
        vt       = valid[t] ? vt : (VT - 1);     // clamp; stores predicated
        vbase[t] = (long)b * V_ + (long)vt * 16;
        const float* arow = evecs + (vbase[t] + r) * K_ + kg * 8;
#pragma unroll
        for (int m = 0; m < 4; ++m) {
            a[t][2 * m]     = *(const float4*)(arow + m * 32);
            a[t][2 * m + 1] = *(const float4*)(arow + m * 32 + 4);
        }
    }

    // ---- B fragments in registers (overlaps A-load latency) ----
    // scale[r] = 10^(-2 + r*2/15) = 2^(r*0.4429237460 - 6.6438561898)
    const float s = exp2f(fmaf((float)r, 0.4429237459849816f,
                               -6.6438561897747246f));
    const float* evb = evals + b * K_ + kg * 8;
    bf16x8 bf[4];
#pragma unroll
    for (int m = 0; m < 4; ++m) {
        const float4 e0 = *(const float4*)(evb + m * 32);
        const float4 e1 = *(const float4*)(evb + m * 32 + 4);
        bf[m][0] = (short)f2bf(__expf(-e0.x * s));
        bf[m][1] = (short)f2bf(__expf(-e0.y * s));
        bf[m][2] = (short)f2bf(__expf(-e0.z * s));
        bf[m][3] = (short)f2bf(__expf(-e0.w * s));
        bf[m][4] = (short)f2bf(__expf(-e1.x * s));
        bf[m][5] = (short)f2bf(__expf(-e1.y * s));
        bf[m][6] = (short)f2bf(__expf(-e1.z * s));
        bf[m][7] = (short)f2bf(__expf(-e1.w * s));
    }

    // ---- square -> bf16 -> MFMA -> store ----
#pragma unroll
    for (int t = 0; t < TPW; ++t) {
        f32x4 acc = {0.f, 0.f, 0.f, 0.f};
#pragma unroll
        for (int m = 0; m < 4; ++m) {
            const float4 e0 = a[t][2 * m];
            const float4 e1 = a[t][2 * m + 1];
            bf16x8 af;
            af[0] = (short)f2bf(e0.x * e0.x);
            af[1] = (short)f2bf(e0.y * e0.y);
            af[2] = (short)f2bf(e0.z * e0.z);
            af[3] = (short)f2bf(e0.w * e0.w);
            af[4] = (short)f2bf(e1.x * e1.x);
            af[5] = (short)f2bf(e1.y * e1.y);
            af[6] = (short)f2bf(e1.z * e1.z);
            af[7] = (short)f2bf(e1.w * e1.w);
            acc = __builtin_amdgcn_mfma_f32_16x16x32_bf16(af, bf[m], acc,
                                                          0, 0, 0);
        }
        if (valid[t]) {
            // D: col = lane&15 (=c), row = kg*4 + i -> 64 B contig / 16 lanes
#pragma unroll
            for (int i = 0; i < 4; ++i)
                __builtin_nontemporal_store(
                    acc[i], &out[(vbase[t] + kg * 4 + i) * CNT + r]);
        }
    }
}

extern "C" void kernel_launch(void* const* d_in, const int* in_sizes, int n_in,
                              void* d_out, int out_size, void* d_ws, size_t ws_size,
                              hipStream_t stream) {
    const float* evals = (const float*)d_in[0];  // [8,128]
    const float* evecs = (const float*)d_in[1];  // [8,50000,128]
    float* out = (float*)d_out;                  // [8,50000,16]

    dim3 grid(GX, B_);
    heat_mfma<<<grid, TPB, 0, stream>>>(evals, evecs, out);
}